// Round 14
// baseline (173.595 us; speedup 1.0000x reference)
//
#include <hip/hip_runtime.h>
#include <hip/hip_bf16.h>
#include <cstdint>

#define GAMMA 0.001f
// K padded 784 -> 1024 = 8*128 (chunk 7 all-zero). Swizzled fp8 tile layout
// per 128-row tile: addr = tile*131072 + kk*16384 + h*8192 + row*64
//                          + (q ^ ((row>>1)&3))*16
// where source byte k = kk*128 + q*32 + h*16 + [0..15].
#define TILE_BYTES 131072

typedef __attribute__((ext_vector_type(4))) float f32x4;
typedef __attribute__((ext_vector_type(8))) int v8i;
typedef __attribute__((ext_vector_type(8))) short bh8;  // 8 bf16
typedef unsigned char u8;

__device__ inline unsigned pack4_fp8(float4 f) {
  unsigned p = __builtin_amdgcn_cvt_pk_fp8_f32(f.x, f.y, 0, false);
  p = __builtin_amdgcn_cvt_pk_fp8_f32(f.z, f.w, p, true);
  return p;
}

__device__ inline ushort bf16u(float v) {
  __hip_bfloat16 h = __float2bfloat16(v);
  return *(ushort*)&h;
}

// ---------------------------------------------------------------------------
// Kernel 1 (merged): bx < 2048 -> conv pair (images 2bx, 2bx+1)
//                    bx >= 2048 -> support prep (rows (bx-2048)*4 + wave)
// Conv2 on the MATRIX pipe (R11-proven): stage1 emits HWC bf16 (a1h), stage2
// is 13 pos-tiles x 3 MFMA(16x16x32 bf16) per image (D=A*B^T).
// ---------------------------------------------------------------------------
__global__ __launch_bounds__(256, 4) void conv_prep_kernel(
    const float* __restrict__ x, const float* __restrict__ w1,
    const float* __restrict__ b1, const float* __restrict__ w2,
    const float* __restrict__ b2, const float* __restrict__ support,
    const float* __restrict__ alpha, u8* __restrict__ feats_t,
    u8* __restrict__ sup_t, float* __restrict__ beta,
    float* __restrict__ ef) {
  int tid = threadIdx.x;
  int bx = blockIdx.x;

  if (bx >= 2048) {  // ---- support prep: wave per row ----
    int lane = tid & 63, wave = tid >> 6;
    int m = (bx - 2048) * 4 + wave;
    const float* row = support + (size_t)m * 784;
    int mt = m >> 7, mr = m & 127;
    u8* tb = sup_t + (size_t)mt * TILE_BYTES;
    float ss = 0.f;
    // 16B unit j = lane covers source bytes 16j..16j+15 (valid j<49)
    uint4 w;
    if (lane < 49) {
      float4 f0 = ((const float4*)row)[lane * 4 + 0];
      float4 f1 = ((const float4*)row)[lane * 4 + 1];
      float4 f2 = ((const float4*)row)[lane * 4 + 2];
      float4 f3 = ((const float4*)row)[lane * 4 + 3];
      ss = f0.x * f0.x + f0.y * f0.y + f0.z * f0.z + f0.w * f0.w +
           f1.x * f1.x + f1.y * f1.y + f1.z * f1.z + f1.w * f1.w +
           f2.x * f2.x + f2.y * f2.y + f2.z * f2.z + f2.w * f2.w +
           f3.x * f3.x + f3.y * f3.y + f3.z * f3.z + f3.w * f3.w;
      w.x = pack4_fp8(f0); w.y = pack4_fp8(f1);
      w.z = pack4_fp8(f2); w.w = pack4_fp8(f3);
    } else {
      w.x = 0; w.y = 0; w.z = 0; w.w = 0;
    }
    int kk = lane >> 3, u = lane & 7, q = u >> 1, h = u & 1;
    int qs = q ^ ((mr >> 1) & 3);
    *(uint4*)(tb + kk * 16384 + h * 8192 + mr * 64 + qs * 16) = w;
#pragma unroll
    for (int s = 1; s < 64; s <<= 1) ss += __shfl_xor(ss, s, 64);
    if (lane == 0) {
      float es = __expf(-GAMMA * ss);
      float4 a = ((const float4*)alpha)[m];
      float4 b;
      b.x = es * a.x; b.y = es * a.y; b.z = es * a.z; b.w = es * a.w;
      ((float4*)beta)[m] = b;
    }
    return;
  }

  // ---- conv pair ----
  __shared__ float xp[2][900];                 // 30x30 zero-padded input
  __shared__ alignas(16) ushort a1h[2][2048];  // HWC bf16: (row*16+col)*8+ic
  __shared__ float w1s[72], b1s[8], b2s[16];
  __shared__ float w2s[1152];                  // raw w2 [oc][ic][9]
  __shared__ alignas(8) ushort sc[2][16][212]; // conv2 out bf16 [oc][pos]
  __shared__ alignas(16) u8 fb[2][784];
  __shared__ float red[256];

  int lane = tid & 63, wave = tid >> 6;

  for (int t = tid; t < 1800; t += 256) ((float*)xp)[t] = 0.f;
  for (int t = tid; t < 1024; t += 256) ((uint4*)a1h)[t] = (uint4){0, 0, 0, 0};
  if (tid < 72) w1s[tid] = w1[tid];
  if (tid < 8) b1s[tid] = b1[tid];
  if (tid < 16) b2s[tid] = b2[tid];
  for (int t = tid; t < 1152; t += 256) w2s[t] = w2[t];
  __syncthreads();

  // build per-lane B-frags (weights): oc=lane&15, quad covers k=quad*8+j,
  // k=(tap=g*4+quad, ic=j); taps>=9 are zero.
  int oc = lane & 15, quad = lane >> 4;
  bh8 wf[3];
#pragma unroll
  for (int g = 0; g < 3; g++) {
    int tap = g * 4 + quad;
#pragma unroll
    for (int j = 0; j < 8; j++) {
      float v = (tap < 9) ? w2s[oc * 72 + j * 9 + tap] : 0.f;
      wf[g][j] = (short)bf16u(v);
    }
  }

  for (int t = tid; t < 392; t += 256) {
    int img = t >= 196, j = t - img * 196;
    float4 v = ((const float4*)(x + (size_t)(bx * 2 + img) * 784))[j];
    int r = j / 7, c = (j % 7) * 4;
    float* p = &xp[img][(r + 1) * 30 + (c + 1)];
    p[0] = v.x; p[1] = v.y; p[2] = v.z; p[3] = v.w;
  }
  __syncthreads();

  // stage 1: conv1(3x3,SAME)+bias+relu+maxpool2 -> a1h (HWC bf16) interiors
  for (int idx = tid; idx < 3136; idx += 256) {
    int img = idx >= 1568;
    int rem = idx - img * 1568;
    int c = rem / 196, r2 = rem % 196;
    int ph = r2 / 14, pw = r2 % 14;
    const float* w = &w1s[c * 9];
    const float* xb = &xp[img][(2 * ph) * 30 + (2 * pw)];
    float t[4][4];
#pragma unroll
    for (int a = 0; a < 4; a++) {
      float2 u0 = *(const float2*)(xb + a * 30);
      float2 u1 = *(const float2*)(xb + a * 30 + 2);
      t[a][0] = u0.x; t[a][1] = u0.y; t[a][2] = u1.x; t[a][3] = u1.y;
    }
    float s00 = 0, s01 = 0, s10 = 0, s11 = 0;
#pragma unroll
    for (int dy = 0; dy < 3; dy++)
#pragma unroll
      for (int dx = 0; dx < 3; dx++) {
        float wv = w[dy * 3 + dx];
        s00 += t[dy][dx] * wv;     s01 += t[dy][dx + 1] * wv;
        s10 += t[dy + 1][dx] * wv; s11 += t[dy + 1][dx + 1] * wv;
      }
    float mx = fmaxf(fmaxf(s00, s01), fmaxf(s10, s11));
    float val = fmaxf(mx + b1s[c], 0.f);
    a1h[img][((ph + 1) * 16 + (pw + 1)) * 8 + c] = bf16u(val);
  }
  __syncthreads();

  // stage 2 (MFMA): waves 0,1 -> img0 tiles 0-6/7-12; waves 2,3 -> img1.
  {
    int img2 = wave >> 1, half = wave & 1;
    int Tstart = half * 7, Tcnt = half ? 6 : 7;
    const ushort* abase = a1h[img2];
    int mrow = lane & 15;  // A-row (pos-in-tile) during reads
    for (int t = 0; t < Tcnt; ++t) {
      int T = Tstart + t;
      int p = T * 16 + mrow;
      int pc = p > 195 ? 195 : p;
      int y = pc / 14, xq = pc - y * 14;
      int cell = y * 16 + xq;
      f32x4 acc = (f32x4){0, 0, 0, 0};
#pragma unroll
      for (int g = 0; g < 3; g++) {
        int tap = g * 4 + quad;
        const ushort* ap;
        if (g == 2 && quad > 0) {
          ap = abase;  // border cell (0,0): guaranteed zeros
        } else {
          int dy = tap / 3, dx = tap - dy * 3;
          ap = abase + (cell + dy * 16 + dx) * 8;
        }
        bh8 af = *(const bh8*)ap;
        acc = __builtin_amdgcn_mfma_f32_16x16x32_bf16(af, wf[g], acc, 0, 0, 0);
      }
      // D: col=lane&15=oc, row=quad*4+r = pos-in-tile
      int pos0 = T * 16 + quad * 4;
      ushort4 s4;
      s4.x = bf16u(acc.x); s4.y = bf16u(acc.y);
      s4.z = bf16u(acc.z); s4.w = bf16u(acc.w);
      *(ushort4*)(&sc[img2][oc][pos0]) = s4;
    }
  }
  __syncthreads();

  // pooling + bias + relu + fp8 + fsq from sc
  int img = tid >> 7, r = tid & 127;
  float fsq = 0.f;
  if (r < 112) {
    int o = r & 15, y7 = r >> 4;
    const ushort* srow = sc[img][o];
    float bo = b2s[o];
#pragma unroll
    for (int x7 = 0; x7 < 7; x7++) {
      int p = 28 * y7 + 2 * x7;
      unsigned u0 = *(const unsigned*)(&srow[p]);
      unsigned u1 = *(const unsigned*)(&srow[p + 14]);
      float a = __uint_as_float(u0 << 16);
      float b = __uint_as_float(u0 & 0xffff0000u);
      float c = __uint_as_float(u1 << 16);
      float d = __uint_as_float(u1 & 0xffff0000u);
      float mx = fmaxf(fmaxf(a, b), fmaxf(c, d));
      float val = fmaxf(mx + bo, 0.f);
      fb[img][o * 49 + y7 * 7 + x7] =
          (u8)(__builtin_amdgcn_cvt_pk_fp8_f32(val, 0.f, 0, false) & 0xff);
      fsq += val * val;
    }
  }
  red[tid] = fsq;
  __syncthreads();
  for (int s = 64; s > 0; s >>= 1) {
    if ((tid & 127) < s) red[tid] += red[tid + s];
    __syncthreads();
  }
  if ((tid & 127) == 0) ef[bx * 2 + img] = __expf(-GAMMA * red[tid]);

  // store feats: 2 imgs x 64 16B-units (units >=49 zero) into swizzled tiles
  if (tid < 128) {
    int im = tid >= 64, j = tid - im * 64;
    uint4 v;
    if (j < 49) v = ((const uint4*)fb[im])[j];
    else { v.x = 0; v.y = 0; v.z = 0; v.w = 0; }
    int n = bx * 2 + im;
    int nt = n >> 7, nr = n & 127;
    int kk = j >> 3, u = j & 7, q = u >> 1, h = u & 1;
    int qs = q ^ ((nr >> 1) & 3);
    *(uint4*)(feats_t + (size_t)nt * TILE_BYTES + kk * 16384 + h * 8192 +
              nr * 64 + qs * 16) = v;
  }
}

// ---------------------------------------------------------------------------
// Kernel 2: fused RBF GEMM, MX-fp8 K=128 MFMA (scales=1.0). One 128x128
// tile/block; grid 2048 = 32 nb x 64 mchunk (chunk=bx&63 -> XCD-L2-resident
// B). BK=256: TWO K-chunks staged per barrier-pair -> 4 drains instead of 7
// (R3-proven move; per-kk wall is ~55% drain stall at 2 blocks/CU). LDS
// 64KB/block still = 2 blocks/CU (no occupancy drop, unlike m132's 3->2).
// launch_bounds(256,2) ONLY — NEVER tighter: (256,4)/(256,5) collapse the
// allocator to 64/48 VGPR -> accumulator spills (R12: WRITE 307MB, 2.1x
// slower; R5 same). R13 clean: VGPR=120, WRITE 8MB.
// Epilogue: contention-free per-chunk partials (R7-proven).
// ---------------------------------------------------------------------------
__global__ __launch_bounds__(256, 2) void rbf_gemm_kernel(
    const u8* __restrict__ feats_t, const u8* __restrict__ sup_t,
    const float* __restrict__ beta, float* __restrict__ partial) {
  __shared__ alignas(16) u8 As[2][16384];
  __shared__ alignas(16) u8 Bs[2][16384];
  int tid = threadIdx.x;
  int wave = tid >> 6, lane = tid & 63;
  int bx = blockIdx.x;
  int chunk = bx & 63, nb = bx >> 6;
  const u8* at = feats_t + (size_t)nb * TILE_BYTES;
  const u8* bt = sup_t + (size_t)chunk * TILE_BYTES;
  int wn = wave >> 1, wm = wave & 1;
  int col = lane & 15, quad = lane >> 4;
  int slot = quad ^ ((col >> 1) & 3);

  f32x4 acc[4][4];
#pragma unroll
  for (int i = 0; i < 4; i++)
#pragma unroll
    for (int j = 0; j < 4; j++) acc[i][j] = (f32x4){0, 0, 0, 0};

  for (int kp = 0; kp < 4; ++kp) {
#pragma unroll
    for (int h2 = 0; h2 < 2; h2++) {
      int kk = kp * 2 + h2;
      const u8* ak = at + kk * 16384 + tid * 16;
      const u8* bk = bt + kk * 16384 + tid * 16;
      u8* la = As[h2] + tid * 16;
      u8* lb = Bs[h2] + tid * 16;
#pragma unroll
      for (int s = 0; s < 4; s++) {
        __builtin_amdgcn_global_load_lds(
            (const __attribute__((address_space(1))) void*)(ak + s * 4096),
            (__attribute__((address_space(3))) void*)(la + s * 4096), 16, 0, 0);
        __builtin_amdgcn_global_load_lds(
            (const __attribute__((address_space(1))) void*)(bk + s * 4096),
            (__attribute__((address_space(3))) void*)(lb + s * 4096), 16, 0, 0);
      }
    }
    __syncthreads();
#pragma unroll
    for (int h2 = 0; h2 < 2; h2++) {
      v8i av[4], bv[4];
#pragma unroll
      for (int i = 0; i < 4; i++) {
        const u8* p = As[h2] + (wn * 64 + i * 16 + col) * 64 + slot * 16;
        int4 lo = *(const int4*)p;
        int4 hi = *(const int4*)(p + 8192);
        av[i] = (v8i){lo.x, lo.y, lo.z, lo.w, hi.x, hi.y, hi.z, hi.w};
      }
#pragma unroll
      for (int j = 0; j < 4; j++) {
        const u8* p = Bs[h2] + (wm * 64 + j * 16 + col) * 64 + slot * 16;
        int4 lo = *(const int4*)p;
        int4 hi = *(const int4*)(p + 8192);
        bv[j] = (v8i){lo.x, lo.y, lo.z, lo.w, hi.x, hi.y, hi.z, hi.w};
      }
#pragma unroll
      for (int i = 0; i < 4; i++)
#pragma unroll
        for (int j = 0; j < 4; j++)
          acc[i][j] = __builtin_amdgcn_mfma_scale_f32_16x16x128_f8f6f4(
              av[i], bv[j], acc[i][j], 0, 0, 0, 0x7f7f7f7f, 0, 0x7f7f7f7f);
    }
    __syncthreads();
  }

  // epilogue: Kv = exp(2*gamma*G) in place (C/D: col=m-idx, quad*4+rr=n-idx)
#pragma unroll
  for (int i = 0; i < 4; i++)
#pragma unroll
    for (int j = 0; j < 4; j++) {
      acc[i][j].x = __expf(2.f * GAMMA * acc[i][j].x);
      acc[i][j].y = __expf(2.f * GAMMA * acc[i][j].y);
      acc[i][j].z = __expf(2.f * GAMMA * acc[i][j].z);
      acc[i][j].w = __expf(2.f * GAMMA * acc[i][j].w);
    }
  int n0 = nb * 128, m0 = chunk * 128;
#pragma unroll
  for (int c = 0; c < 4; ++c) {
    float bl[4];
#pragma unroll
    for (int j = 0; j < 4; j++)
      bl[j] = beta[(m0 + wm * 64 + j * 16 + col) * 4 + c];
#pragma unroll
    for (int i = 0; i < 4; i++) {
      f32x4 s = acc[i][0] * bl[0] + acc[i][1] * bl[1] + acc[i][2] * bl[2] +
                acc[i][3] * bl[3];
#pragma unroll
      for (int st = 1; st < 16; st <<= 1) {
        s.x += __shfl_xor(s.x, st, 16);
        s.y += __shfl_xor(s.y, st, 16);
        s.z += __shfl_xor(s.z, st, 16);
        s.w += __shfl_xor(s.w, st, 16);
      }
      if (col == c) {
        int n = n0 + wn * 64 + i * 16 + quad * 4;
        float* pp = partial + (((size_t)chunk * 2 + wm) * 4096 + n) * 4 + c;
        pp[0] = s.x; pp[4] = s.y; pp[8] = s.z; pp[12] = s.w;
      }
    }
  }
}

// ---------------------------------------------------------------------------
// Kernel 3: out[n][0..3] = ef[n] * sum_{128 slots} partial[slot][n][0..3]
// ---------------------------------------------------------------------------
__global__ __launch_bounds__(256) void reduce_kernel(
    const float* __restrict__ partial, const float* __restrict__ ef,
    float* __restrict__ out) {
  __shared__ float4 sred[4][64];
  int nl = threadIdx.x & 63, chq = threadIdx.x >> 6;
  int n = blockIdx.x * 64 + nl;
  const float4* p = (const float4*)partial;
  float sx = 0, sy = 0, sz = 0, sw = 0;
  for (int ch = chq * 32; ch < chq * 32 + 32; ch++) {
    float4 v = p[(size_t)ch * 4096 + n];
    sx += v.x; sy += v.y; sz += v.z; sw += v.w;
  }
  sred[chq][nl] = (float4){sx, sy, sz, sw};
  __syncthreads();
  if (chq == 0) {
    float4 a = sred[0][nl], b = sred[1][nl], c = sred[2][nl], d = sred[3][nl];
    float e = ef[n];
    float4 o;
    o.x = e * (a.x + b.x + c.x + d.x);
    o.y = e * (a.y + b.y + c.y + d.y);
    o.z = e * (a.z + b.z + c.z + d.z);
    o.w = e * (a.w + b.w + c.w + d.w);
    ((float4*)out)[n] = o;
  }
}

// ---------------------------------------------------------------------------
extern "C" void kernel_launch(void* const* d_in, const int* in_sizes, int n_in,
                              void* d_out, int out_size, void* d_ws,
                              size_t ws_size, hipStream_t stream) {
  const float* x = (const float*)d_in[0];
  const float* w1 = (const float*)d_in[1];
  const float* b1 = (const float*)d_in[2];
  const float* w2 = (const float*)d_in[3];
  const float* b2 = (const float*)d_in[4];
  const float* support = (const float*)d_in[5];
  const float* alpha = (const float*)d_in[6];
  float* out = (float*)d_out;

  u8* ws = (u8*)d_ws;
  u8* sup_t = ws;                                 // 64 tiles  = 8,388,608 B
  u8* feats_t = ws + 8388608;                     // 32 tiles  = 4,194,304 B
  float* beta = (float*)(ws + 12582912);          // 8192*4*4  =   131,072 B
  float* ef = (float*)(ws + 12713984);            // 4096*4    =    16,384 B
  float* partial = (float*)(ws + 12730368);       // 128*4096*4*4 = 8,388,608 B

  conv_prep_kernel<<<4096, 256, 0, stream>>>(x, w1, b1, w2, b2, support, alpha,
                                             feats_t, sup_t, beta, ef);
  rbf_gemm_kernel<<<2048, 256, 0, stream>>>(feats_t, sup_t, beta, partial);
  reduce_kernel<<<64, 256, 0, stream>>>(partial, ef, out);
}

// Round 15
// 167.533 us; speedup vs baseline: 1.0362x; 1.0362x over previous
//
#include <hip/hip_runtime.h>
#include <hip/hip_bf16.h>
#include <cstdint>

#define GAMMA 0.001f
// K padded 784 -> 896 = 7*128. Swizzled fp8 tile layout per 128-row tile
// (R8/R9-proven): addr = tile*114688 + kk*16384 + h*8192 + row*64
//                        + (q ^ ((row>>1)&3))*16
// where source byte k = kk*128 + q*32 + h*16 + [0..15].
#define TILE_BYTES 114688

typedef __attribute__((ext_vector_type(4))) float f32x4;
typedef __attribute__((ext_vector_type(8))) int v8i;
typedef __attribute__((ext_vector_type(8))) short bh8;  // 8 bf16
typedef unsigned char u8;

__device__ inline unsigned pack4_fp8(float4 f) {
  unsigned p = __builtin_amdgcn_cvt_pk_fp8_f32(f.x, f.y, 0, false);
  p = __builtin_amdgcn_cvt_pk_fp8_f32(f.z, f.w, p, true);
  return p;
}

__device__ inline ushort bf16u(float v) {
  __hip_bfloat16 h = __float2bfloat16(v);
  return *(ushort*)&h;
}

// ---------------------------------------------------------------------------
// Kernel 1 (merged): bx < 2048 -> conv pair (images 2bx, 2bx+1)
//                    bx >= 2048 -> support prep (rows (bx-2048)*4 + wave)
// Conv2 on the MATRIX pipe (R11-proven): stage1 emits HWC bf16 (a1h), stage2
// is 13 pos-tiles x 3 MFMA(16x16x32 bf16) per image (D=A*B^T).
// ---------------------------------------------------------------------------
__global__ __launch_bounds__(256, 4) void conv_prep_kernel(
    const float* __restrict__ x, const float* __restrict__ w1,
    const float* __restrict__ b1, const float* __restrict__ w2,
    const float* __restrict__ b2, const float* __restrict__ support,
    const float* __restrict__ alpha, u8* __restrict__ feats_t,
    u8* __restrict__ sup_t, float* __restrict__ beta,
    float* __restrict__ ef) {
  int tid = threadIdx.x;
  int bx = blockIdx.x;

  if (bx >= 2048) {  // ---- support prep: wave per row ----
    int lane = tid & 63, wave = tid >> 6;
    int m = (bx - 2048) * 4 + wave;
    const float* row = support + (size_t)m * 784;
    int mt = m >> 7, mr = m & 127;
    u8* tb = sup_t + (size_t)mt * TILE_BYTES;
    float ss = 0.f;
    if (lane < 56) {  // 16B unit j covers source bytes 16j..16j+15
      uint4 w;
      if (lane < 49) {
        float4 f0 = ((const float4*)row)[lane * 4 + 0];
        float4 f1 = ((const float4*)row)[lane * 4 + 1];
        float4 f2 = ((const float4*)row)[lane * 4 + 2];
        float4 f3 = ((const float4*)row)[lane * 4 + 3];
        ss = f0.x * f0.x + f0.y * f0.y + f0.z * f0.z + f0.w * f0.w +
             f1.x * f1.x + f1.y * f1.y + f1.z * f1.z + f1.w * f1.w +
             f2.x * f2.x + f2.y * f2.y + f2.z * f2.z + f2.w * f2.w +
             f3.x * f3.x + f3.y * f3.y + f3.z * f3.z + f3.w * f3.w;
        w.x = pack4_fp8(f0); w.y = pack4_fp8(f1);
        w.z = pack4_fp8(f2); w.w = pack4_fp8(f3);
      } else {
        w.x = 0; w.y = 0; w.z = 0; w.w = 0;
      }
      int kk = lane >> 3, u = lane & 7, q = u >> 1, h = u & 1;
      int qs = q ^ ((mr >> 1) & 3);
      *(uint4*)(tb + kk * 16384 + h * 8192 + mr * 64 + qs * 16) = w;
    }
#pragma unroll
    for (int s = 1; s < 64; s <<= 1) ss += __shfl_xor(ss, s, 64);
    if (lane == 0) {
      float es = __expf(-GAMMA * ss);
      float4 a = ((const float4*)alpha)[m];
      float4 b;
      b.x = es * a.x; b.y = es * a.y; b.z = es * a.z; b.w = es * a.w;
      ((float4*)beta)[m] = b;
    }
    return;
  }

  // ---- conv pair ----
  __shared__ float xp[2][900];                 // 30x30 zero-padded input
  __shared__ alignas(16) ushort a1h[2][2048];  // HWC bf16: (row*16+col)*8+ic
  __shared__ float w1s[72], b1s[8], b2s[16];
  __shared__ float w2s[1152];                  // raw w2 [oc][ic][9]
  __shared__ alignas(8) ushort sc[2][16][212]; // conv2 out bf16 [oc][pos]
  __shared__ alignas(16) u8 fb[2][784];
  __shared__ float red[256];

  int lane = tid & 63, wave = tid >> 6;

  for (int t = tid; t < 1800; t += 256) ((float*)xp)[t] = 0.f;
  for (int t = tid; t < 1024; t += 256) ((uint4*)a1h)[t] = (uint4){0, 0, 0, 0};
  if (tid < 72) w1s[tid] = w1[tid];
  if (tid < 8) b1s[tid] = b1[tid];
  if (tid < 16) b2s[tid] = b2[tid];
  for (int t = tid; t < 1152; t += 256) w2s[t] = w2[t];
  __syncthreads();

  // build per-lane B-frags (weights): oc=lane&15, quad covers k=quad*8+j,
  // k=(tap=g*4+quad, ic=j); taps>=9 are zero.
  int oc = lane & 15, quad = lane >> 4;
  bh8 wf[3];
#pragma unroll
  for (int g = 0; g < 3; g++) {
    int tap = g * 4 + quad;
#pragma unroll
    for (int j = 0; j < 8; j++) {
      float v = (tap < 9) ? w2s[oc * 72 + j * 9 + tap] : 0.f;
      wf[g][j] = (short)bf16u(v);
    }
  }

  for (int t = tid; t < 392; t += 256) {
    int img = t >= 196, j = t - img * 196;
    float4 v = ((const float4*)(x + (size_t)(bx * 2 + img) * 784))[j];
    int r = j / 7, c = (j % 7) * 4;
    float* p = &xp[img][(r + 1) * 30 + (c + 1)];
    p[0] = v.x; p[1] = v.y; p[2] = v.z; p[3] = v.w;
  }
  __syncthreads();

  // stage 1: conv1(3x3,SAME)+bias+relu+maxpool2 -> a1h (HWC bf16) interiors
  for (int idx = tid; idx < 3136; idx += 256) {
    int img = idx >= 1568;
    int rem = idx - img * 1568;
    int c = rem / 196, r2 = rem % 196;
    int ph = r2 / 14, pw = r2 % 14;
    const float* w = &w1s[c * 9];
    const float* xb = &xp[img][(2 * ph) * 30 + (2 * pw)];
    float t[4][4];
#pragma unroll
    for (int a = 0; a < 4; a++) {
      float2 u0 = *(const float2*)(xb + a * 30);
      float2 u1 = *(const float2*)(xb + a * 30 + 2);
      t[a][0] = u0.x; t[a][1] = u0.y; t[a][2] = u1.x; t[a][3] = u1.y;
    }
    float s00 = 0, s01 = 0, s10 = 0, s11 = 0;
#pragma unroll
    for (int dy = 0; dy < 3; dy++)
#pragma unroll
      for (int dx = 0; dx < 3; dx++) {
        float wv = w[dy * 3 + dx];
        s00 += t[dy][dx] * wv;     s01 += t[dy][dx + 1] * wv;
        s10 += t[dy + 1][dx] * wv; s11 += t[dy + 1][dx + 1] * wv;
      }
    float mx = fmaxf(fmaxf(s00, s01), fmaxf(s10, s11));
    float val = fmaxf(mx + b1s[c], 0.f);
    a1h[img][((ph + 1) * 16 + (pw + 1)) * 8 + c] = bf16u(val);
  }
  __syncthreads();

  // stage 2 (MFMA): waves 0,1 -> img0 tiles 0-6/7-12; waves 2,3 -> img1.
  {
    int img2 = wave >> 1, half = wave & 1;
    int Tstart = half * 7, Tcnt = half ? 6 : 7;
    const ushort* abase = a1h[img2];
    int mrow = lane & 15;  // A-row (pos-in-tile) during reads
    for (int t = 0; t < Tcnt; ++t) {
      int T = Tstart + t;
      int p = T * 16 + mrow;
      int pc = p > 195 ? 195 : p;
      int y = pc / 14, xq = pc - y * 14;
      int cell = y * 16 + xq;
      f32x4 acc = (f32x4){0, 0, 0, 0};
#pragma unroll
      for (int g = 0; g < 3; g++) {
        int tap = g * 4 + quad;
        const ushort* ap;
        if (g == 2 && quad > 0) {
          ap = abase;  // border cell (0,0): guaranteed zeros
        } else {
          int dy = tap / 3, dx = tap - dy * 3;
          ap = abase + (cell + dy * 16 + dx) * 8;
        }
        bh8 af = *(const bh8*)ap;
        acc = __builtin_amdgcn_mfma_f32_16x16x32_bf16(af, wf[g], acc, 0, 0, 0);
      }
      // D: col=lane&15=oc, row=quad*4+r = pos-in-tile
      int pos0 = T * 16 + quad * 4;
      ushort4 s4;
      s4.x = bf16u(acc.x); s4.y = bf16u(acc.y);
      s4.z = bf16u(acc.z); s4.w = bf16u(acc.w);
      *(ushort4*)(&sc[img2][oc][pos0]) = s4;
    }
  }
  __syncthreads();

  // pooling + bias + relu + fp8 + fsq from sc
  int img = tid >> 7, r = tid & 127;
  float fsq = 0.f;
  if (r < 112) {
    int o = r & 15, y7 = r >> 4;
    const ushort* srow = sc[img][o];
    float bo = b2s[o];
#pragma unroll
    for (int x7 = 0; x7 < 7; x7++) {
      int p = 28 * y7 + 2 * x7;
      unsigned u0 = *(const unsigned*)(&srow[p]);
      unsigned u1 = *(const unsigned*)(&srow[p + 14]);
      float a = __uint_as_float(u0 << 16);
      float b = __uint_as_float(u0 & 0xffff0000u);
      float c = __uint_as_float(u1 << 16);
      float d = __uint_as_float(u1 & 0xffff0000u);
      float mx = fmaxf(fmaxf(a, b), fmaxf(c, d));
      float val = fmaxf(mx + bo, 0.f);
      fb[img][o * 49 + y7 * 7 + x7] =
          (u8)(__builtin_amdgcn_cvt_pk_fp8_f32(val, 0.f, 0, false) & 0xff);
      fsq += val * val;
    }
  }
  red[tid] = fsq;
  __syncthreads();
  for (int s = 64; s > 0; s >>= 1) {
    if ((tid & 127) < s) red[tid] += red[tid + s];
    __syncthreads();
  }
  if ((tid & 127) == 0) ef[bx * 2 + img] = __expf(-GAMMA * red[tid]);

  // store feats: 2 imgs x 56 16B-units into swizzled tile layout
  if (tid < 112) {
    int im = tid >= 56, j = tid - im * 56;
    uint4 v;
    if (j < 49) v = ((const uint4*)fb[im])[j];
    else { v.x = 0; v.y = 0; v.z = 0; v.w = 0; }
    int n = bx * 2 + im;
    int nt = n >> 7, nr = n & 127;
    int kk = j >> 3, u = j & 7, q = u >> 1, h = u & 1;
    int qs = q ^ ((nr >> 1) & 3);
    *(uint4*)(feats_t + (size_t)nt * TILE_BYTES + kk * 16384 + h * 8192 +
              nr * 64 + qs * 16) = v;
  }
}

// ---------------------------------------------------------------------------
// Kernel 2: fused RBF GEMM, MX-fp8 K=128 MFMA (scales=1.0). One 128x128
// tile/block; grid 2048 = 32 nb x 64 mchunk (chunk=bx&63 -> XCD-L2-resident
// B, FETCH 18MB measured). BK=128, 7 K-iters (R14 measured BK=256 is WORSE:
// 63.9 vs 59.1us — zero-chunk padding + longer drains eat the barrier win).
// launch_bounds(256,2) ONLY — NEVER tighter: (256,4)/(256,5) collapse the
// allocator to 64/48 VGPR -> accumulator spills (R12 WRITE 307MB, 2.1x
// slower; R5 same). R13 clean: VGPR=120, WRITE 8MB, 59.1us.
// Epilogue: contention-free per-chunk partials (R7-proven).
// ---------------------------------------------------------------------------
__global__ __launch_bounds__(256, 2) void rbf_gemm_kernel(
    const u8* __restrict__ feats_t, const u8* __restrict__ sup_t,
    const float* __restrict__ beta, float* __restrict__ partial) {
  __shared__ alignas(16) u8 As[16384];
  __shared__ alignas(16) u8 Bs[16384];
  int tid = threadIdx.x;
  int wave = tid >> 6, lane = tid & 63;
  int bx = blockIdx.x;
  int chunk = bx & 63, nb = bx >> 6;
  const u8* at = feats_t + (size_t)nb * TILE_BYTES;
  const u8* bt = sup_t + (size_t)chunk * TILE_BYTES;
  int wn = wave >> 1, wm = wave & 1;
  int col = lane & 15, quad = lane >> 4;
  int slot = quad ^ ((col >> 1) & 3);

  f32x4 acc[4][4];
#pragma unroll
  for (int i = 0; i < 4; i++)
#pragma unroll
    for (int j = 0; j < 4; j++) acc[i][j] = (f32x4){0, 0, 0, 0};

  for (int kk = 0; kk < 7; ++kk) {
    const u8* ak = at + kk * 16384 + tid * 16;
    const u8* bk = bt + kk * 16384 + tid * 16;
    u8* la = As + tid * 16;
    u8* lb = Bs + tid * 16;
#pragma unroll
    for (int s = 0; s < 4; s++) {
      __builtin_amdgcn_global_load_lds(
          (const __attribute__((address_space(1))) void*)(ak + s * 4096),
          (__attribute__((address_space(3))) void*)(la + s * 4096), 16, 0, 0);
      __builtin_amdgcn_global_load_lds(
          (const __attribute__((address_space(1))) void*)(bk + s * 4096),
          (__attribute__((address_space(3))) void*)(lb + s * 4096), 16, 0, 0);
    }
    __syncthreads();
    v8i av[4], bv[4];
#pragma unroll
    for (int i = 0; i < 4; i++) {
      const u8* p = As + (wn * 64 + i * 16 + col) * 64 + slot * 16;
      int4 lo = *(const int4*)p;
      int4 hi = *(const int4*)(p + 8192);
      av[i] = (v8i){lo.x, lo.y, lo.z, lo.w, hi.x, hi.y, hi.z, hi.w};
    }
#pragma unroll
    for (int j = 0; j < 4; j++) {
      const u8* p = Bs + (wm * 64 + j * 16 + col) * 64 + slot * 16;
      int4 lo = *(const int4*)p;
      int4 hi = *(const int4*)(p + 8192);
      bv[j] = (v8i){lo.x, lo.y, lo.z, lo.w, hi.x, hi.y, hi.z, hi.w};
    }
#pragma unroll
    for (int i = 0; i < 4; i++)
#pragma unroll
      for (int j = 0; j < 4; j++)
        acc[i][j] = __builtin_amdgcn_mfma_scale_f32_16x16x128_f8f6f4(
            av[i], bv[j], acc[i][j], 0, 0, 0, 0x7f7f7f7f, 0, 0x7f7f7f7f);
    __syncthreads();
  }

  // epilogue: Kv = exp(2*gamma*G) in place (C/D: col=m-idx, quad*4+rr=n-idx)
#pragma unroll
  for (int i = 0; i < 4; i++)
#pragma unroll
    for (int j = 0; j < 4; j++) {
      acc[i][j].x = __expf(2.f * GAMMA * acc[i][j].x);
      acc[i][j].y = __expf(2.f * GAMMA * acc[i][j].y);
      acc[i][j].z = __expf(2.f * GAMMA * acc[i][j].z);
      acc[i][j].w = __expf(2.f * GAMMA * acc[i][j].w);
    }
  int n0 = nb * 128, m0 = chunk * 128;
#pragma unroll
  for (int c = 0; c < 4; ++c) {
    float bl[4];
#pragma unroll
    for (int j = 0; j < 4; j++)
      bl[j] = beta[(m0 + wm * 64 + j * 16 + col) * 4 + c];
#pragma unroll
    for (int i = 0; i < 4; i++) {
      f32x4 s = acc[i][0] * bl[0] + acc[i][1] * bl[1] + acc[i][2] * bl[2] +
                acc[i][3] * bl[3];
#pragma unroll
      for (int st = 1; st < 16; st <<= 1) {
        s.x += __shfl_xor(s.x, st, 16);
        s.y += __shfl_xor(s.y, st, 16);
        s.z += __shfl_xor(s.z, st, 16);
        s.w += __shfl_xor(s.w, st, 16);
      }
      if (col == c) {
        int n = n0 + wn * 64 + i * 16 + quad * 4;
        float* pp = partial + (((size_t)chunk * 2 + wm) * 4096 + n) * 4 + c;
        pp[0] = s.x; pp[4] = s.y; pp[8] = s.z; pp[12] = s.w;
      }
    }
  }
}

// ---------------------------------------------------------------------------
// Kernel 3: out[n][0..3] = ef[n] * sum_{128 slots} partial[slot][n][0..3]
// ---------------------------------------------------------------------------
__global__ __launch_bounds__(256) void reduce_kernel(
    const float* __restrict__ partial, const float* __restrict__ ef,
    float* __restrict__ out) {
  __shared__ float4 sred[4][64];
  int nl = threadIdx.x & 63, chq = threadIdx.x >> 6;
  int n = blockIdx.x * 64 + nl;
  const float4* p = (const float4*)partial;
  float sx = 0, sy = 0, sz = 0, sw = 0;
  for (int ch = chq * 32; ch < chq * 32 + 32; ch++) {
    float4 v = p[(size_t)ch * 4096 + n];
    sx += v.x; sy += v.y; sz += v.z; sw += v.w;
  }
  sred[chq][nl] = (float4){sx, sy, sz, sw};
  __syncthreads();
  if (chq == 0) {
    float4 a = sred[0][nl], b = sred[1][nl], c = sred[2][nl], d = sred[3][nl];
    float e = ef[n];
    float4 o;
    o.x = e * (a.x + b.x + c.x + d.x);
    o.y = e * (a.y + b.y + c.y + d.y);
    o.z = e * (a.z + b.z + c.z + d.z);
    o.w = e * (a.w + b.w + c.w + d.w);
    ((float4*)out)[n] = o;
  }
}

// ---------------------------------------------------------------------------
extern "C" void kernel_launch(void* const* d_in, const int* in_sizes, int n_in,
                              void* d_out, int out_size, void* d_ws,
                              size_t ws_size, hipStream_t stream) {
  const float* x = (const float*)d_in[0];
  const float* w1 = (const float*)d_in[1];
  const float* b1 = (const float*)d_in[2];
  const float* w2 = (const float*)d_in[3];
  const float* b2 = (const float*)d_in[4];
  const float* support = (const float*)d_in[5];
  const float* alpha = (const float*)d_in[6];
  float* out = (float*)d_out;

  u8* ws = (u8*)d_ws;
  u8* sup_t = ws;                                 // 64 tiles  = 7,340,032 B
  u8* feats_t = ws + 7340032;                     // 32 tiles  = 3,670,016 B
  float* beta = (float*)(ws + 11010048);          // 8192*4*4  =   131,072 B
  float* ef = (float*)(ws + 11141120);            // 4096*4    =    16,384 B
  float* partial = (float*)(ws + 11157504);       // 128*4096*4*4 = 8,388,608 B

  conv_prep_kernel<<<4096, 256, 0, stream>>>(x, w1, b1, w2, b2, support, alpha,
                                             feats_t, sup_t, beta, ef);
  rbf_gemm_kernel<<<2048, 256, 0, stream>>>(feats_t, sup_t, beta, partial);
  reduce_kernel<<<64, 256, 0, stream>>>(partial, ef, out);
}